// Round 1
// baseline (618.273 us; speedup 1.0000x reference)
//
#include <hip/hip_runtime.h>
#include <hip/hip_bf16.h>

// Problem constants
#define B_    32
#define C_    256
#define HW_   3136   // 56*56
#define OC_   256
#define M_    8
#define KPB_  589824 // per-sample wl elements: 8*9*256*32 = 2304*256

typedef short v8s __attribute__((ext_vector_type(8)));   // 8 x bf16 (4 VGPRs)
typedef float f32x4 __attribute__((ext_vector_type(4)));

// ---------------------------------------------------------------------------
// 1) Global average pool: gap[b][c] = mean over 3136 pixels. One wave per row.
__global__ void gap_kernel(const float* __restrict__ x, float* __restrict__ gap) {
    int wid  = (blockIdx.x * blockDim.x + threadIdx.x) >> 6;  // [0, 8192)
    int lane = threadIdx.x & 63;
    const float* row = x + (size_t)wid * HW_;
    float s = 0.f;
    for (int j = lane; j < HW_; j += 64) s += row[j];
    for (int off = 32; off; off >>= 1) s += __shfl_xor(s, off, 64);
    if (lane == 0) gap[wid] = s * (1.0f / HW_);
}

// ---------------------------------------------------------------------------
// 2) Gate + softmax: alpha[b][m]. One wave per sample.
__global__ void alpha_kernel(const float* __restrict__ gap,
                             const float* __restrict__ gate_w,
                             const float* __restrict__ gate_b,
                             float* __restrict__ alpha) {
    int b = blockIdx.x, lane = threadIdx.x;
    float g0 = gap[b*C_ + lane],       g1 = gap[b*C_ + 64 + lane];
    float g2 = gap[b*C_ + 128 + lane], g3 = gap[b*C_ + 192 + lane];
    float logit[M_];
    #pragma unroll
    for (int m = 0; m < M_; ++m) {
        const float* w = gate_w + m*C_;
        float s = g0*w[lane] + g1*w[64+lane] + g2*w[128+lane] + g3*w[192+lane];
        for (int off = 32; off; off >>= 1) s += __shfl_xor(s, off, 64);
        logit[m] = s + gate_b[m];   // every lane has the full sum
    }
    float mx = logit[0];
    #pragma unroll
    for (int m = 1; m < M_; ++m) mx = fmaxf(mx, logit[m]);
    float den = 0.f, e[M_];
    #pragma unroll
    for (int m = 0; m < M_; ++m) { e[m] = __expf(logit[m] - mx); den += e[m]; }
    float mine = 0.f;
    #pragma unroll
    for (int m = 0; m < M_; ++m) if (lane == m) mine = e[m];
    if (lane < M_) alpha[b*M_ + lane] = mine / den;
}

// ---------------------------------------------------------------------------
// 3) Combined bias: biasc[b][o] = sum_m alpha[b][m] * bias[m][o]
__global__ void biasc_kernel(const float* __restrict__ bias,
                             const float* __restrict__ alpha,
                             float* __restrict__ biasc) {
    int b = blockIdx.x, o = threadIdx.x;
    float s = 0.f;
    #pragma unroll
    for (int m = 0; m < M_; ++m) s += alpha[b*M_+m] * bias[m*OC_+o];
    biasc[b*OC_+o] = s;
}

// ---------------------------------------------------------------------------
// 4) x (f32, BCHW) -> xhwc (bf16, B,HW,C). LDS tile transpose, 64x64.
__global__ __launch_bounds__(256) void xcast_kernel(const float* __restrict__ x,
                                                    __hip_bfloat16* __restrict__ xhwc) {
    __shared__ __hip_bfloat16 tile[64][65];
    int b = blockIdx.z, ct = blockIdx.y, pt = blockIdx.x;
    int p0 = pt*64, c0 = ct*64;
    int tp = threadIdx.x & 63, tc = threadIdx.x >> 6;
    const float* xb = x + ((size_t)b*C_ + c0) * HW_ + p0;
    #pragma unroll
    for (int j = 0; j < 16; ++j) {
        int cl = tc + j*4;
        tile[cl][tp] = __float2bfloat16(xb[(size_t)cl*HW_ + tp]);
    }
    __syncthreads();
    __hip_bfloat16* ob = xhwc + ((size_t)b*HW_ + p0) * C_ + c0;
    #pragma unroll
    for (int j = 0; j < 16; ++j) {
        int pl = tc + j*4;
        ob[(size_t)pl*C_ + tp] = tile[tp][pl];
    }
}

// ---------------------------------------------------------------------------
// 5) Combine expert kernels into per-sample weights, MFMA-A-friendly layout:
//    wl[b][i_blk(8)][tap(9)][o(256)][i_in(32)]  (bf16)
//    Each thread owns one (i_blk,tap,o,i_in), reads its 8 expert values once,
//    emits all 32 samples (writes contiguous per 256-thread block).
__global__ __launch_bounds__(256) void combine_kernel(const float* __restrict__ weight,
                                                      const float* __restrict__ alpha,
                                                      __hip_bfloat16* __restrict__ wl) {
    __shared__ float as[B_*M_];
    as[threadIdx.x] = alpha[threadIdx.x];
    __syncthreads();
    int g    = blockIdx.x*256 + threadIdx.x;   // [0, 589824)
    int i_in = g & 31;
    int o    = (g >> 5) & 255;
    int t2   = g >> 13;
    int tap  = t2 % 9;
    int ib   = t2 / 9;
    int i    = ib*32 + i_in;
    int base = o*2304 + i*9 + tap;             // weight[m][o][i][kh][kw] flat (per m)
    float wv[M_];
    #pragma unroll
    for (int m = 0; m < M_; ++m) wv[m] = weight[(size_t)m*589824 + base];
    for (int b = 0; b < B_; ++b) {
        float s = 0.f;
        #pragma unroll
        for (int m = 0; m < M_; ++m) s += as[b*M_+m] * wv[m];
        wl[(size_t)b*KPB_ + g] = __float2bfloat16(s);
    }
}

// ---------------------------------------------------------------------------
// 6) Implicit-GEMM conv via MFMA bf16 16x16x32.
//    GEMM per sample: C[o(256), p(3136)] = sum_k A[o,k] * B[k,p], K = 2304
//    k ordered (i_blk, tap, i_in32) to match wl; B built on the fly from xhwc
//    with per-lane boundary masking (tap offset constant within each K-block).
//    Block = 4 waves = 128o x 128p; wave = 64o x 64p (4x4 fragments).
__global__ __launch_bounds__(256) void conv_kernel(const __hip_bfloat16* __restrict__ xhwc,
                                                   const __hip_bfloat16* __restrict__ wl,
                                                   const float* __restrict__ biasc,
                                                   float* __restrict__ out) {
    int b   = blockIdx.z;
    int ot  = blockIdx.y;   // 0..1
    int pt  = blockIdx.x;   // 0..24
    int tid = threadIdx.x;
    int wave = tid >> 6, lane = tid & 63;
    int q = lane >> 4, ln = lane & 15;
    int o_base = ot*128 + (wave >> 1)*64;
    int p_base = pt*128 + (wave & 1)*64;

    int p_lane[4], hh[4], wc[4];
    #pragma unroll
    for (int c = 0; c < 4; ++c) {
        int p = p_base + c*16 + ln;
        p_lane[c] = p; hh[c] = p / 56; wc[c] = p % 56;
    }

    f32x4 acc[4][4];
    #pragma unroll
    for (int r = 0; r < 4; ++r)
        #pragma unroll
        for (int c = 0; c < 4; ++c) acc[r][c] = (f32x4){0.f, 0.f, 0.f, 0.f};

    const short* xb = (const short*)xhwc + (size_t)b * HW_ * C_;
    const short* wb = (const short*)wl   + (size_t)b * KPB_;
    const v8s vzero = {};

    for (int ib = 0; ib < 8; ++ib) {
        #pragma unroll
        for (int tap = 0; tap < 9; ++tap) {
            const int dh = tap/3 - 1, dw = tap%3 - 1;
            const short* wa = wb + ((ib*9 + tap) << 13) + q*8;   // 8192 = 256*32
            v8s a[4];
            #pragma unroll
            for (int r = 0; r < 4; ++r)
                a[r] = *(const v8s*)(wa + (o_base + r*16 + ln)*32);
            v8s bf[4];
            #pragma unroll
            for (int c = 0; c < 4; ++c) {
                int h2 = hh[c] + dh, w2 = wc[c] + dw;
                bool valid = ((unsigned)h2 < 56u) && ((unsigned)w2 < 56u);
                int pp = p_lane[c] + dh*56 + dw;
                pp = pp < 0 ? 0 : (pp > HW_-1 ? HW_-1 : pp);
                v8s v = *(const v8s*)(xb + pp*256 + ib*32 + q*8);
                bf[c] = valid ? v : vzero;
            }
            #pragma unroll
            for (int r = 0; r < 4; ++r)
                #pragma unroll
                for (int c = 0; c < 4; ++c)
                    acc[r][c] = __builtin_amdgcn_mfma_f32_16x16x32_bf16(a[r], bf[c], acc[r][c], 0, 0, 0);
        }
    }

    // Epilogue: D[row=o][col=p], col=lane&15, row=quad*4+reg (verified mapping)
    #pragma unroll
    for (int c = 0; c < 4; ++c) {
        int p = p_lane[c];
        if (p >= HW_) continue;
        #pragma unroll
        for (int r = 0; r < 4; ++r) {
            int o0 = o_base + r*16 + q*4;
            float* op = out + (size_t)b * OC_ * HW_ + p;
            #pragma unroll
            for (int reg = 0; reg < 4; ++reg) {
                int o = o0 + reg;
                op[(size_t)o * HW_] = acc[r][c][reg] + biasc[b*OC_ + o];
            }
        }
    }
}

// ---------------------------------------------------------------------------
extern "C" void kernel_launch(void* const* d_in, const int* in_sizes, int n_in,
                              void* d_out, int out_size, void* d_ws, size_t ws_size,
                              hipStream_t stream) {
    const float* x      = (const float*)d_in[0];
    const float* weight = (const float*)d_in[1];
    const float* bias   = (const float*)d_in[2];
    const float* gate_w = (const float*)d_in[3];
    const float* gate_b = (const float*)d_in[4];
    float* out = (float*)d_out;

    // Workspace layout (bytes):
    //   xhwc  @ 0          : 32*3136*256*2 = 51,380,224
    //   wl    @ 51,380,224 : 32*589824*2   = 37,748,736
    //   gap   @ 89,128,960 : 32*256*4      = 32,768
    //   alpha @ 89,161,728 : 32*8*4        = 1,024
    //   biasc @ 89,162,752 : 32*256*4      = 32,768
    char* ws = (char*)d_ws;
    __hip_bfloat16* xhwc  = (__hip_bfloat16*)(ws);
    __hip_bfloat16* wl    = (__hip_bfloat16*)(ws + 51380224);
    float*          gap   = (float*)(ws + 89128960);
    float*          alpha = (float*)(ws + 89161728);
    float*          biasc = (float*)(ws + 89162752);

    gap_kernel   <<<2048, 256, 0, stream>>>(x, gap);
    alpha_kernel <<<32,    64, 0, stream>>>(gap, gate_w, gate_b, alpha);
    biasc_kernel <<<32,   256, 0, stream>>>(bias, alpha, biasc);
    xcast_kernel <<<dim3(49, 4, 32), 256, 0, stream>>>(x, xhwc);
    combine_kernel<<<2304, 256, 0, stream>>>(weight, alpha, wl);
    conv_kernel  <<<dim3(25, 2, 32), 256, 0, stream>>>(xhwc, wl, biasc, out);
}

// Round 2
// 399.918 us; speedup vs baseline: 1.5460x; 1.5460x over previous
//
#include <hip/hip_runtime.h>
#include <hip/hip_bf16.h>

// Problem constants
#define B_    32
#define C_    256
#define HW_   3136   // 56*56
#define OC_   256
#define M_    8
#define KPB_  589824 // per-sample wl shorts: 72 kblocks * 8192

typedef short v8s __attribute__((ext_vector_type(8)));   // 8 x bf16 (4 VGPRs)
typedef float f32x4 __attribute__((ext_vector_type(4)));

__device__ __forceinline__ void gll16(const short* src, short* dst) {
    __builtin_amdgcn_global_load_lds((const __attribute__((address_space(1))) void*)src,
                                     (__attribute__((address_space(3))) void*)dst, 16, 0, 0);
}

// ---------------------------------------------------------------------------
// 0) zero the gap accumulator (ws is poisoned 0xAA before every launch)
__global__ void zero_gap_kernel(float* __restrict__ gap) {
    gap[blockIdx.x * 256 + threadIdx.x] = 0.f;
}

// ---------------------------------------------------------------------------
// 1) x (f32, BCHW) -> xg (bf16, [b][ib=8][p][32] channel-blocked), fused with
//    global-average-pool partial sums (atomicAdd into gap, zeroed beforehand).
__global__ __launch_bounds__(256) void xcast_kernel(const float* __restrict__ x,
                                                    __hip_bfloat16* __restrict__ xg,
                                                    float* __restrict__ gap) {
    __shared__ __hip_bfloat16 tile[64][65];
    int b = blockIdx.z, ct = blockIdx.y, pt = blockIdx.x;
    int p0 = pt*64, c0 = ct*64;
    int tp = threadIdx.x & 63, tc = threadIdx.x >> 6;   // tc == wave id
    const float* xb = x + ((size_t)b*C_ + c0) * HW_ + p0;
    #pragma unroll
    for (int j = 0; j < 16; ++j) {
        int cl = tc + j*4;
        float v = xb[(size_t)cl*HW_ + tp];
        tile[cl][tp] = __float2bfloat16(v);
        float s = v;
        #pragma unroll
        for (int off = 32; off; off >>= 1) s += __shfl_xor(s, off, 64);
        if (tp == 0) atomicAdd(&gap[b*C_ + c0 + cl], s);
    }
    __syncthreads();
    #pragma unroll
    for (int j = 0; j < 16; ++j) {
        int pl = tc + j*4;
        int p  = p0 + pl;
        int c  = c0 + tp;
        xg[(((size_t)b*8 + (c>>5))*HW_ + p)*32 + (c & 31)] = tile[tp][pl];
    }
}

// ---------------------------------------------------------------------------
// 2) Gate + softmax: alpha[b][m]. One wave per sample. gap holds SUMS.
__global__ void alpha_kernel(const float* __restrict__ gap,
                             const float* __restrict__ gate_w,
                             const float* __restrict__ gate_b,
                             float* __restrict__ alpha) {
    int b = blockIdx.x, lane = threadIdx.x;
    const float inv = 1.0f / HW_;
    float g0 = gap[b*C_ + lane]*inv,       g1 = gap[b*C_ + 64 + lane]*inv;
    float g2 = gap[b*C_ + 128 + lane]*inv, g3 = gap[b*C_ + 192 + lane]*inv;
    float logit[M_];
    #pragma unroll
    for (int m = 0; m < M_; ++m) {
        const float* w = gate_w + m*C_;
        float s = g0*w[lane] + g1*w[64+lane] + g2*w[128+lane] + g3*w[192+lane];
        for (int off = 32; off; off >>= 1) s += __shfl_xor(s, off, 64);
        logit[m] = s + gate_b[m];
    }
    float mx = logit[0];
    #pragma unroll
    for (int m = 1; m < M_; ++m) mx = fmaxf(mx, logit[m]);
    float den = 0.f, e[M_];
    #pragma unroll
    for (int m = 0; m < M_; ++m) { e[m] = __expf(logit[m] - mx); den += e[m]; }
    float mine = 0.f;
    #pragma unroll
    for (int m = 0; m < M_; ++m) if (lane == m) mine = e[m];
    if (lane < M_) alpha[b*M_ + lane] = mine / den;
}

// ---------------------------------------------------------------------------
// 3) Combined bias: biasc[b][o] = sum_m alpha[b][m] * bias[m][o]
__global__ void biasc_kernel(const float* __restrict__ bias,
                             const float* __restrict__ alpha,
                             float* __restrict__ biasc) {
    int b = blockIdx.x, o = threadIdx.x;
    float s = 0.f;
    #pragma unroll
    for (int m = 0; m < M_; ++m) s += alpha[b*M_+m] * bias[m*OC_+o];
    biasc[b*OC_+o] = s;
}

// ---------------------------------------------------------------------------
// 4) Combine expert kernels: wl[b][ib(8)][tap(9)][o(256)][i_in(32)] bf16
__global__ __launch_bounds__(256) void combine_kernel(const float* __restrict__ weight,
                                                      const float* __restrict__ alpha,
                                                      __hip_bfloat16* __restrict__ wl) {
    __shared__ float as[B_*M_];
    as[threadIdx.x] = alpha[threadIdx.x];
    __syncthreads();
    int g    = blockIdx.x*256 + threadIdx.x;   // [0, 589824)
    int i_in = g & 31;
    int o    = (g >> 5) & 255;
    int t2   = g >> 13;
    int tap  = t2 % 9;
    int ib   = t2 / 9;
    int i    = ib*32 + i_in;
    int base = o*2304 + i*9 + tap;             // weight[m][o][i][kh][kw] flat
    float wv[M_];
    #pragma unroll
    for (int m = 0; m < M_; ++m) wv[m] = weight[(size_t)m*589824 + base];
    for (int b = 0; b < B_; ++b) {
        float s = 0.f;
        #pragma unroll
        for (int m = 0; m < M_; ++m) s += as[b*M_+m] * wv[m];
        wl[(size_t)b*KPB_ + g] = __float2bfloat16(s);
    }
}

// ---------------------------------------------------------------------------
// 5) Implicit-GEMM conv, MFMA bf16 16x16x32, m97-style LDS double-buffer.
//    Block = 128o x 128p (4 waves of 64x64). K-step = one (ib,tap) pair (K=32).
//    A-tile 8KB and shifted-B-tile 8KB staged per step via global_load_lds(16B).
//    Out-of-range B sources only ever feed masked (cndmask-zeroed) lanes.
__global__ __launch_bounds__(256, 3) void conv_kernel(const short* __restrict__ xg,
                                                      const short* __restrict__ wl,
                                                      const float* __restrict__ biasc,
                                                      float* __restrict__ out) {
    __shared__ short smem[2][8192];   // per buffer: A @ [0,4096), B @ [4096,8192) shorts
    const int b = blockIdx.z, ot = blockIdx.y, pt = blockIdx.x;
    const int tid = threadIdx.x;
    const int wave = tid >> 6, lane = tid & 63, q = lane >> 4, ln = lane & 15;
    const int o_half = wave >> 1, p_half = wave & 1;
    const int p_base = pt*128 + p_half*64;

    const int DOFF[9] = {-57,-56,-55,-1,0,1,55,56,57};

    unsigned vmask[4]; int p_lane[4];
    #pragma unroll
    for (int c = 0; c < 4; ++c) {
        int p = p_base + c*16 + ln;
        p_lane[c] = p;
        int h = p/56, w = p%56;
        unsigned m = 0;
        #pragma unroll
        for (int tap = 0; tap < 9; ++tap) {
            int h2 = h + tap/3 - 1, w2 = w + tap%3 - 1;
            if ((unsigned)h2 < 56u && (unsigned)w2 < 56u) m |= (1u << tap);
        }
        vmask[c] = m;
    }

    const short* wbase = wl + (size_t)b*KPB_ + (size_t)ot*4096 + tid*8;
    const short* xbase = xg + (size_t)(b*8)*HW_*32 + tid*8;

    auto stage = [&](int kidx, int ib, int doff, int buf) {
        const short* asrc = wbase + (size_t)kidx*8192;
        gll16(asrc,        &smem[buf][tid*8]);
        gll16(asrc + 2048, &smem[buf][tid*8 + 2048]);
        const short* bsrc = xbase + ((long)ib*HW_ + pt*128 + doff)*32;
        gll16(bsrc,        &smem[buf][4096 + tid*8]);
        gll16(bsrc + 2048, &smem[buf][4096 + tid*8 + 2048]);
    };

    f32x4 acc[4][4];
    #pragma unroll
    for (int r = 0; r < 4; ++r)
        #pragma unroll
        for (int c = 0; c < 4; ++c) acc[r][c] = (f32x4){0.f,0.f,0.f,0.f};

    const int aoff = (o_half*64 + ln)*32 + q*8;          // shorts; + r*512
    const int boff = 4096 + (p_half*64 + ln)*32 + q*8;   // shorts; + c*512
    const v8s vzero = {};

    stage(0, 0, DOFF[0], 0);

    for (int ib = 0; ib < 8; ++ib) {
        #pragma unroll
        for (int tap = 0; tap < 9; ++tap) {
            const int k = ib*9 + tap;
            const int cur = k & 1;
            __syncthreads();   // staging of `cur` done; prior reads of cur^1 done
            if (k + 1 < 72) {
                int tap2 = (tap == 8) ? 0 : tap + 1;
                int ib2  = (tap == 8) ? ib + 1 : ib;
                stage(k + 1, ib2, DOFF[tap2], cur ^ 1);
            }
            const short* sm = smem[cur];
            v8s a[4], bf[4];
            #pragma unroll
            for (int r = 0; r < 4; ++r) a[r] = *(const v8s*)(sm + aoff + r*512);
            #pragma unroll
            for (int c = 0; c < 4; ++c) {
                v8s v = *(const v8s*)(sm + boff + c*512);
                bf[c] = ((vmask[c] >> tap) & 1) ? v : vzero;
            }
            #pragma unroll
            for (int r = 0; r < 4; ++r)
                #pragma unroll
                for (int c = 0; c < 4; ++c)
                    acc[r][c] = __builtin_amdgcn_mfma_f32_16x16x32_bf16(a[r], bf[c], acc[r][c], 0, 0, 0);
        }
    }

    // Epilogue: D[row=o][col=p], col=lane&15, row=quad*4+reg
    const int o_block = ot*128 + o_half*64;
    #pragma unroll
    for (int c = 0; c < 4; ++c) {
        int p = p_lane[c];
        if (p >= HW_) continue;
        float* op = out + (size_t)b * OC_ * HW_ + p;
        #pragma unroll
        for (int r = 0; r < 4; ++r) {
            int o0 = o_block + r*16 + q*4;
            #pragma unroll
            for (int reg = 0; reg < 4; ++reg) {
                int o = o0 + reg;
                op[(size_t)o * HW_] = acc[r][c][reg] + biasc[b*OC_ + o];
            }
        }
    }
}

// ---------------------------------------------------------------------------
extern "C" void kernel_launch(void* const* d_in, const int* in_sizes, int n_in,
                              void* d_out, int out_size, void* d_ws, size_t ws_size,
                              hipStream_t stream) {
    const float* x      = (const float*)d_in[0];
    const float* weight = (const float*)d_in[1];
    const float* bias   = (const float*)d_in[2];
    const float* gate_w = (const float*)d_in[3];
    const float* gate_b = (const float*)d_in[4];
    float* out = (float*)d_out;

    // Workspace layout (bytes):
    //   gap   @ 0       : 32*256*4 = 32,768
    //   biasc @ 32768   : 32,768
    //   alpha @ 65536   : 1,024
    //   (pad — also absorbs conv's small negative B-staging overruns)
    //   xg    @ 131072  : 32*8*3136*32*2 = 51,380,224
    //   wl    @ 51,511,296 : 32*589824*2 = 37,748,736   (absorbs tail overruns)
    char* ws = (char*)d_ws;
    float*          gap   = (float*)(ws);
    float*          biasc = (float*)(ws + 32768);
    float*          alpha = (float*)(ws + 65536);
    __hip_bfloat16* xg    = (__hip_bfloat16*)(ws + 131072);
    __hip_bfloat16* wl    = (__hip_bfloat16*)(ws + 51511296);

    zero_gap_kernel<<<32, 256, 0, stream>>>(gap);
    xcast_kernel   <<<dim3(49, 4, 32), 256, 0, stream>>>(x, xg, gap);
    alpha_kernel   <<<32,  64, 0, stream>>>(gap, gate_w, gate_b, alpha);
    biasc_kernel   <<<32, 256, 0, stream>>>(bias, alpha, biasc);
    combine_kernel <<<2304, 256, 0, stream>>>(weight, alpha, wl);
    conv_kernel    <<<dim3(25, 2, 32), 256, 0, stream>>>((const short*)xg, (const short*)wl, biasc, out);
}

// Round 3
// 395.198 us; speedup vs baseline: 1.5645x; 1.0119x over previous
//
#include <hip/hip_runtime.h>
#include <hip/hip_bf16.h>

// Problem constants
#define B_    32
#define C_    256
#define HW_   3136   // 56*56
#define OC_   256
#define M_    8
#define KPB_  589824 // per-sample wl shorts: 72 kblocks * 8192

typedef short v8s __attribute__((ext_vector_type(8)));   // 8 x bf16 (4 VGPRs)
typedef float f32x4 __attribute__((ext_vector_type(4)));

union bf8pack { v8s v; __hip_bfloat16 h[8]; };

__device__ __forceinline__ void gll16(const short* src, short* dst) {
    __builtin_amdgcn_global_load_lds((const __attribute__((address_space(1))) void*)src,
                                     (__attribute__((address_space(3))) void*)dst, 16, 0, 0);
}

// ---------------------------------------------------------------------------
// 0) zero the gap accumulator (ws is poisoned 0xAA before every launch)
__global__ void zero_gap_kernel(float* __restrict__ gap) {
    gap[blockIdx.x * 256 + threadIdx.x] = 0.f;
}

// ---------------------------------------------------------------------------
// 1) x (f32, BCHW) -> xg (bf16, [b][ib=8][p][32] channel-blocked), fused GAP.
//    Store phase emits 16B per thread (8 contiguous channels per pixel).
__global__ __launch_bounds__(256) void xcast_kernel(const float* __restrict__ x,
                                                    short* __restrict__ xg,
                                                    float* __restrict__ gap) {
    __shared__ __hip_bfloat16 tile[64][65];   // [channel][pixel], +1 pad
    int b = blockIdx.z, ct = blockIdx.y, pt = blockIdx.x;
    int p0 = pt*64, c0 = ct*64;
    int tp = threadIdx.x & 63, tc = threadIdx.x >> 6;
    const float* xb = x + ((size_t)b*C_ + c0) * HW_ + p0;
    #pragma unroll
    for (int j = 0; j < 16; ++j) {
        int cl = tc + j*4;
        float v = xb[(size_t)cl*HW_ + tp];
        tile[cl][tp] = __float2bfloat16(v);
        float s = v;
        #pragma unroll
        for (int off = 32; off; off >>= 1) s += __shfl_xor(s, off, 64);
        if (tp == 0) atomicAdd(&gap[b*C_ + c0 + cl], s);
    }
    __syncthreads();
    // 64 px * 8 chunks(8ch) = 512 v8s stores, 2 per thread
    #pragma unroll
    for (int it = 0; it < 2; ++it) {
        int idx = it*256 + threadIdx.x;
        int px = idx >> 3, ck = idx & 7;
        bf8pack pk;
        #pragma unroll
        for (int j = 0; j < 8; ++j) pk.h[j] = tile[ck*8 + j][px];
        int c = c0 + ck*8;
        size_t dst = (((size_t)b*8 + (c >> 5))*HW_ + p0 + px)*32 + (c & 31);
        *(v8s*)(xg + dst) = pk.v;
    }
}

// ---------------------------------------------------------------------------
// 2) Gate softmax + combined bias, fused. One wave per sample. gap holds SUMS.
__global__ void alpha_kernel(const float* __restrict__ gap,
                             const float* __restrict__ gate_w,
                             const float* __restrict__ gate_b,
                             const float* __restrict__ bias,
                             float* __restrict__ alpha,
                             float* __restrict__ biasc) {
    int b = blockIdx.x, lane = threadIdx.x;
    const float inv = 1.0f / HW_;
    float g0 = gap[b*C_ + lane]*inv,       g1 = gap[b*C_ + 64 + lane]*inv;
    float g2 = gap[b*C_ + 128 + lane]*inv, g3 = gap[b*C_ + 192 + lane]*inv;
    float logit[M_];
    #pragma unroll
    for (int m = 0; m < M_; ++m) {
        const float* w = gate_w + m*C_;
        float s = g0*w[lane] + g1*w[64+lane] + g2*w[128+lane] + g3*w[192+lane];
        for (int off = 32; off; off >>= 1) s += __shfl_xor(s, off, 64);
        logit[m] = s + gate_b[m];
    }
    float mx = logit[0];
    #pragma unroll
    for (int m = 1; m < M_; ++m) mx = fmaxf(mx, logit[m]);
    float den = 0.f, e[M_];
    #pragma unroll
    for (int m = 0; m < M_; ++m) { e[m] = __expf(logit[m] - mx); den += e[m]; }
    float am[M_];
    #pragma unroll
    for (int m = 0; m < M_; ++m) am[m] = e[m] / den;   // every lane has all alphas
    if (lane < M_) alpha[b*M_ + lane] = am[lane];
    #pragma unroll
    for (int r = 0; r < 4; ++r) {
        int o = r*64 + lane;
        float s = 0.f;
        #pragma unroll
        for (int m = 0; m < M_; ++m) s += am[m] * bias[m*OC_ + o];
        biasc[b*OC_ + o] = s;
    }
}

// ---------------------------------------------------------------------------
// 3) Combine expert kernels: wl[b][ib(8)][tap(9)][o(256)][i_in(32)] bf16.
//    Each thread: one 8-channel chunk, reads 64 expert floats once, emits all
//    32 samples as 16B stores.
__global__ __launch_bounds__(256) void combine_kernel(const float* __restrict__ weight,
                                                      const float* __restrict__ alpha,
                                                      short* __restrict__ wl) {
    __shared__ float as[B_*M_];
    as[threadIdx.x] = alpha[threadIdx.x];
    __syncthreads();
    int gc  = blockIdx.x*256 + threadIdx.x;   // [0, 73728)
    int i8  = gc & 3;
    int o   = (gc >> 2) & 255;
    int t2  = gc >> 10;
    int tap = t2 % 9;
    int ib  = t2 / 9;
    int base = o*2304 + (ib*32 + i8*8)*9 + tap;   // + j*9
    float wv[M_][8];
    #pragma unroll
    for (int m = 0; m < M_; ++m)
        #pragma unroll
        for (int j = 0; j < 8; ++j)
            wv[m][j] = weight[(size_t)m*589824 + base + j*9];
    for (int b = 0; b < B_; ++b) {
        bf8pack pk;
        #pragma unroll
        for (int j = 0; j < 8; ++j) {
            float s = 0.f;
            #pragma unroll
            for (int m = 0; m < M_; ++m) s += as[b*M_+m] * wv[m][j];
            pk.h[j] = __float2bfloat16(s);
        }
        *(v8s*)(wl + (size_t)b*KPB_ + (size_t)gc*8) = pk.v;
    }
}

// ---------------------------------------------------------------------------
// 4) Implicit-GEMM conv, MFMA bf16 16x16x32.
//    Block = 128o x 256p, 4 waves of 64o x 128p (acc 4x8). Per ib: B staged
//    ONCE as a 384-px halo tile (24 KB) serving all 9 taps at shifted offsets;
//    A (8 KB) double-buffered per (ib,tap). LDS = 64 KB.
__global__ __launch_bounds__(256, 2) void conv_kernel(const short* __restrict__ xg,
                                                      const short* __restrict__ wl,
                                                      const float* __restrict__ biasc,
                                                      float* __restrict__ out) {
    __shared__ short smem[32768];  // 64 KB: A0@0, A1@4096, B0@8192, B1@20480 (shorts)
    const int b = blockIdx.z, ot = blockIdx.y, pt = blockIdx.x;
    const int tid = threadIdx.x;
    const int wave = tid >> 6, lane = tid & 63, q = lane >> 4, ln = lane & 15;
    const int o_half = wave >> 1, p_half = wave & 1;
    const int P0 = pt*256;

    const int DOFF[9] = {-57,-56,-55,-1,0,1,55,56,57};

    unsigned vmask[8]; int p_lane[8];
    #pragma unroll
    for (int c = 0; c < 8; ++c) {
        int p = P0 + p_half*128 + c*16 + ln;
        p_lane[c] = p;
        int h = p/56, w = p%56;
        unsigned m = 0;
        #pragma unroll
        for (int tap = 0; tap < 9; ++tap) {
            int h2 = h + tap/3 - 1, w2 = w + tap%3 - 1;
            if ((unsigned)h2 < 56u && (unsigned)w2 < 56u) m |= (1u << tap);
        }
        vmask[c] = m;
    }

    const short* wbase = wl + (size_t)b*KPB_ + ot*4096 + tid*8;
    const short* xbase = xg + (size_t)(b*8)*HW_*32;

    auto stageA = [&](int kidx, int buf) {
        const short* src = wbase + (size_t)kidx*8192;
        gll16(src,        &smem[buf*4096 + tid*8]);
        gll16(src + 2048, &smem[buf*4096 + tid*8 + 2048]);
    };
    auto stageB = [&](int ib, int buf) {   // 384 px halo: [P0-64, P0+320)
        const short* src = xbase + ((long)ib*HW_ + P0 - 64)*32 + tid*8;
        short* dst = &smem[8192 + buf*12288 + tid*8];
        #pragma unroll
        for (int r = 0; r < 6; ++r) gll16(src + r*2048, dst + r*2048);
    };

    f32x4 acc[4][8];
    #pragma unroll
    for (int r = 0; r < 4; ++r)
        #pragma unroll
        for (int c = 0; c < 8; ++c) acc[r][c] = (f32x4){0.f,0.f,0.f,0.f};

    stageA(0, 0);
    stageB(0, 0);

    const int a_lane_off = (o_half*64 + ln)*32 + q*8;           // + r*512
    const int b_lane_off = (64 + p_half*128 + ln)*32 + q*8;     // + c*512 + doff*32
    const v8s vzero = {};

    for (int ib = 0; ib < 8; ++ib) {
        const short* bbuf = &smem[8192 + (ib & 1)*12288 + b_lane_off];
        #pragma unroll
        for (int tap = 0; tap < 9; ++tap) {
            const int k = ib*9 + tap;
            __syncthreads();
            if (k + 1 < 72) stageA(k + 1, (k + 1) & 1);
            if (tap == 0 && ib < 7) stageB(ib + 1, (ib + 1) & 1);

            const short* am = &smem[(k & 1)*4096 + a_lane_off];
            v8s a[4];
            #pragma unroll
            for (int r = 0; r < 4; ++r) a[r] = *(const v8s*)(am + r*512);
            const short* bm = bbuf + DOFF[tap]*32;
            #pragma unroll
            for (int c = 0; c < 8; ++c) {
                v8s v = *(const v8s*)(bm + c*512);
                v8s bf = ((vmask[c] >> tap) & 1) ? v : vzero;
                #pragma unroll
                for (int r = 0; r < 4; ++r)
                    acc[r][c] = __builtin_amdgcn_mfma_f32_16x16x32_bf16(a[r], bf, acc[r][c], 0, 0, 0);
            }
        }
    }

    // Epilogue: D[row=o][col=p], col=lane&15, row=quad*4+reg
    const int o_block = ot*128 + o_half*64;
    #pragma unroll
    for (int c = 0; c < 8; ++c) {
        int p = p_lane[c];
        if (p >= HW_) continue;
        float* op = out + (size_t)b * OC_ * HW_ + p;
        #pragma unroll
        for (int r = 0; r < 4; ++r) {
            int o0 = o_block + r*16 + q*4;
            #pragma unroll
            for (int reg = 0; reg < 4; ++reg) {
                int o = o0 + reg;
                op[(size_t)o * HW_] = acc[r][c][reg] + biasc[b*OC_ + o];
            }
        }
    }
}

// ---------------------------------------------------------------------------
extern "C" void kernel_launch(void* const* d_in, const int* in_sizes, int n_in,
                              void* d_out, int out_size, void* d_ws, size_t ws_size,
                              hipStream_t stream) {
    const float* x      = (const float*)d_in[0];
    const float* weight = (const float*)d_in[1];
    const float* bias   = (const float*)d_in[2];
    const float* gate_w = (const float*)d_in[3];
    const float* gate_b = (const float*)d_in[4];
    float* out = (float*)d_out;

    // Workspace layout (bytes):
    //   gap   @ 0       : 32,768
    //   biasc @ 32768   : 32,768
    //   alpha @ 65536   : 1,024
    //   (pad — absorbs conv's B-halo negative overrun, up to -4 KB)
    //   xg    @ 131072  : 32*8*3136*32*2 = 51,380,224
    //   wl    @ 51,511,296 : 32*589824*2 = 37,748,736 (absorbs B-halo tail overrun)
    char* ws = (char*)d_ws;
    float* gap   = (float*)(ws);
    float* biasc = (float*)(ws + 32768);
    float* alpha = (float*)(ws + 65536);
    short* xg    = (short*)(ws + 131072);
    short* wl    = (short*)(ws + 51511296);

    zero_gap_kernel<<<32, 256, 0, stream>>>(gap);
    xcast_kernel   <<<dim3(49, 4, 32), 256, 0, stream>>>(x, xg, gap);
    alpha_kernel   <<<32,  64, 0, stream>>>(gap, gate_w, gate_b, bias, alpha, biasc);
    combine_kernel <<<288, 256, 0, stream>>>(weight, alpha, wl);
    conv_kernel    <<<dim3(13, 2, 32), 256, 0, stream>>>(xg, wl, biasc, out);
}